// Round 14
// baseline (553.786 us; speedup 1.0000x reference)
//
#include <hip/hip_runtime.h>
#include <hip/hip_bf16.h>
#include <math.h>
#include <stdint.h>

#define N_NODES 49152
#define N_EDGES 196608
#define NB      2048
#define HIDDEN  256
#define LAT     128
#define FHID    256
#define NFLOWS  4
#define MA      38
#define NNF_    38
#define NEF_    4

typedef __attribute__((ext_vector_type(8))) short bf16x8;
typedef __attribute__((ext_vector_type(4))) float f32x4;

#define MEMPIN() asm volatile("" ::: "memory")
#define BARRIER() asm volatile("s_waitcnt lgkmcnt(0)\n\ts_barrier" ::: "memory")
#define SBAR() __builtin_amdgcn_s_barrier()
#define WAITV0() { asm volatile("s_waitcnt vmcnt(0)" ::: "memory"); __builtin_amdgcn_sched_barrier(0); }
#define WAITV2() { asm volatile("s_waitcnt vmcnt(2)" ::: "memory"); __builtin_amdgcn_sched_barrier(0); }
#define WAITV4() { asm volatile("s_waitcnt vmcnt(4)" ::: "memory"); __builtin_amdgcn_sched_barrier(0); }
#define MFMA16 __builtin_amdgcn_mfma_f32_16x16x32_bf16

// ---------- bf16 helpers ----------
__device__ inline uint32_t bf16_rne_bits(float v){
    uint32_t u = __float_as_uint(v);
    u += 0x7fffu + ((u >> 16) & 1u);
    return u & 0xffff0000u;
}
__device__ inline uint16_t to_b16(float v){ return (uint16_t)(bf16_rne_bits(v) >> 16); }
__device__ inline float from_b16(uint16_t u){ return __uint_as_float((uint32_t)u << 16); }
__device__ inline uint32_t pack_hl(float v){
    uint32_t hu = bf16_rne_bits(v);
    float r = v - __uint_as_float(hu);
    uint32_t lu = bf16_rne_bits(r);
    return hu | (lu >> 16);
}

__device__ inline void unpack_frag(const uint4& x, const uint4& y, bf16x8& hi, bf16x8& lo){
    union { bf16x8 v; uint32_t u[4]; } H, L;
    H.u[0] = __builtin_amdgcn_perm(x.y, x.x, 0x07060302u);
    H.u[1] = __builtin_amdgcn_perm(x.w, x.z, 0x07060302u);
    H.u[2] = __builtin_amdgcn_perm(y.y, y.x, 0x07060302u);
    H.u[3] = __builtin_amdgcn_perm(y.w, y.z, 0x07060302u);
    L.u[0] = __builtin_amdgcn_perm(x.y, x.x, 0x05040100u);
    L.u[1] = __builtin_amdgcn_perm(x.w, x.z, 0x05040100u);
    L.u[2] = __builtin_amdgcn_perm(y.y, y.x, 0x05040100u);
    L.u[3] = __builtin_amdgcn_perm(y.w, y.z, 0x05040100u);
    hi = H.v; lo = L.v;
}

// ---------------- init / CSR build ----------------

__global__ void k_init(int* __restrict__ cursor, int* __restrict__ gstart, int* __restrict__ gcnt){
    int i = blockIdx.x*256 + threadIdx.x;
    if (i < N_NODES) cursor[i] = 0;
    if (i < NB){ gstart[i] = 0x7fffffff; gcnt[i] = 0; }
}

__global__ void k_embed(const int* __restrict__ x, const float* __restrict__ emb, uint16_t* __restrict__ h){
    int i = blockIdx.x; int c = threadIdx.x;
    h[(size_t)i*HIDDEN + c] = to_b16(emb[x[i]*HIDDEN + c]);
}

__global__ void k_deg(const int* __restrict__ dst, int* __restrict__ cursor){
    int e = blockIdx.x*256 + threadIdx.x;
    if (e < N_EDGES) atomicAdd(&cursor[dst[e]], 1);
}

__global__ void k_meta(const int* __restrict__ batch, int* __restrict__ gstart, int* __restrict__ gcnt){
    int i = blockIdx.x*256 + threadIdx.x;
    if (i < N_NODES){ int b = batch[i]; atomicMin(&gstart[b], i); atomicAdd(&gcnt[b], 1); }
}

__global__ __launch_bounds__(1024) void k_scan(int* __restrict__ cursor, int* __restrict__ offs){
    __shared__ int part[1024];
    const int tid = threadIdx.x;
    const int CH = N_NODES/1024; // 48
    int local[48];
    int s = 0;
    int base = tid*CH;
    for (int j=0;j<CH;j++){ local[j] = cursor[base+j]; s += local[j]; }
    part[tid] = s;
    __syncthreads();
    for (int off=1; off<1024; off<<=1){
        int v = (tid>=off) ? part[tid-off] : 0;
        __syncthreads();
        part[tid] += v;
        __syncthreads();
    }
    int excl = (tid==0) ? 0 : part[tid-1];
    for (int j=0;j<CH;j++){ offs[base+j] = excl; excl += local[j]; cursor[base+j] = 0; }
    if (tid == 1023) offs[N_NODES] = excl;
}

__global__ void k_scatter(const int* __restrict__ src, const int* __restrict__ dst, const int* __restrict__ attr,
                          const int* __restrict__ offs, int* __restrict__ cursor, int* __restrict__ epack){
    int e = blockIdx.x*256 + threadIdx.x;
    if (e < N_EDGES){
        int d = dst[e];
        int pos = atomicAdd(&cursor[d], 1);
        epack[offs[d] + pos] = (src[e] & 0xffff) | (attr[e] << 16);
    }
}

// ---------------- message aggregation: wave-per-node, 4-edge MLP chunks ----------------

__global__ __launch_bounds__(256) void k_aggr(const uint16_t* __restrict__ h, const float* __restrict__ eemb,
                                              const int* __restrict__ offs, const int* __restrict__ epack,
                                              uint16_t* __restrict__ t){
    __shared__ float sE[NEF_*HIDDEN];
    const int tid  = threadIdx.x;
    #pragma unroll
    for (int q=0;q<NEF_;q++) sE[q*256 + tid] = eemb[q*256 + tid];
    __syncthreads();

    const int wave = tid >> 6;
    const int lane = tid & 63;
    const int node = blockIdx.x*4 + wave;
    const int c4   = lane*4;

    uint2 hu = *(const uint2*)(h + (size_t)node*HIDDEN + c4);
    float4 acc;
    acc.x = __uint_as_float(hu.x << 16);
    acc.y = __uint_as_float(hu.x & 0xffff0000u);
    acc.z = __uint_as_float(hu.y << 16);
    acc.w = __uint_as_float(hu.y & 0xffff0000u);

    const int e0 = offs[node], e1 = offs[node+1];
    for (int j = e0; j < e1; j += 4){
        int p0 = epack[j];
        int p1 = (j+1 < e1) ? epack[j+1] : p0;
        int p2 = (j+2 < e1) ? epack[j+2] : p0;
        int p3 = (j+3 < e1) ? epack[j+3] : p0;
        uint2 g0 = *(const uint2*)(h + (size_t)(p0 & 0xffff)*HIDDEN + c4);
        uint2 g1 = *(const uint2*)(h + (size_t)(p1 & 0xffff)*HIDDEN + c4);
        uint2 g2 = *(const uint2*)(h + (size_t)(p2 & 0xffff)*HIDDEN + c4);
        uint2 g3 = *(const uint2*)(h + (size_t)(p3 & 0xffff)*HIDDEN + c4);
        {
            const float4 ev = *(const float4*)&sE[(p0 >> 16)*HIDDEN + c4];
            acc.x += fmaxf(__uint_as_float(g0.x << 16)        + ev.x, 0.f);
            acc.y += fmaxf(__uint_as_float(g0.x & 0xffff0000u) + ev.y, 0.f);
            acc.z += fmaxf(__uint_as_float(g0.y << 16)        + ev.z, 0.f);
            acc.w += fmaxf(__uint_as_float(g0.y & 0xffff0000u) + ev.w, 0.f);
        }
        if (j+1 < e1){
            const float4 ev = *(const float4*)&sE[(p1 >> 16)*HIDDEN + c4];
            acc.x += fmaxf(__uint_as_float(g1.x << 16)        + ev.x, 0.f);
            acc.y += fmaxf(__uint_as_float(g1.x & 0xffff0000u) + ev.y, 0.f);
            acc.z += fmaxf(__uint_as_float(g1.y << 16)        + ev.z, 0.f);
            acc.w += fmaxf(__uint_as_float(g1.y & 0xffff0000u) + ev.w, 0.f);
        }
        if (j+2 < e1){
            const float4 ev = *(const float4*)&sE[(p2 >> 16)*HIDDEN + c4];
            acc.x += fmaxf(__uint_as_float(g2.x << 16)        + ev.x, 0.f);
            acc.y += fmaxf(__uint_as_float(g2.x & 0xffff0000u) + ev.y, 0.f);
            acc.z += fmaxf(__uint_as_float(g2.y << 16)        + ev.z, 0.f);
            acc.w += fmaxf(__uint_as_float(g2.y & 0xffff0000u) + ev.w, 0.f);
        }
        if (j+3 < e1){
            const float4 ev = *(const float4*)&sE[(p3 >> 16)*HIDDEN + c4];
            acc.x += fmaxf(__uint_as_float(g3.x << 16)        + ev.x, 0.f);
            acc.y += fmaxf(__uint_as_float(g3.x & 0xffff0000u) + ev.y, 0.f);
            acc.z += fmaxf(__uint_as_float(g3.y << 16)        + ev.z, 0.f);
            acc.w += fmaxf(__uint_as_float(g3.y & 0xffff0000u) + ev.w, 0.f);
        }
    }

    uint2 o;
    o.x = (uint32_t)to_b16(acc.x) | ((uint32_t)to_b16(acc.y) << 16);
    o.y = (uint32_t)to_b16(acc.z) | ((uint32_t)to_b16(acc.w) << 16);
    *(uint2*)(t + (size_t)node*HIDDEN + c4) = o;
}

// ---------------- fused weight / activation converter (single launch) ----------------

#define CVT_TOTAL 4489216

__global__ void k_cvt_all(
    const float* __restrict__ conv_w1, const float* __restrict__ conv_w2,
    const float* __restrict__ mu_w, const float* __restrict__ mu_b,
    const float* __restrict__ lv_w, const float* __restrict__ lv_b,
    const float* __restrict__ fw1, const float* __restrict__ fw2,
    const float* __restrict__ dn_w1, const float* __restrict__ dn_w2,
    const float* __restrict__ de_w1, const float* __restrict__ de_w2,
    const float* __restrict__ de_b2,
    uint16_t* __restrict__ cw1b, uint16_t* __restrict__ cw2b,
    uint32_t* __restrict__ mvwpk, float* __restrict__ mvb,
    uint16_t* __restrict__ w1p, uint16_t* __restrict__ w2p,
    uint16_t* __restrict__ dnw1b, uint16_t* __restrict__ dnw2b,
    uint16_t* __restrict__ dew1b, uint16_t* __restrict__ dew2b,
    float* __restrict__ deb2s)
{
    int i = blockIdx.x*256 + threadIdx.x;
    if (i < 262144){
        int o = (i >> 8) & 255, k = i & 255;
        int dst = (i & ~65535) | ((k >> 3) << 11) | (o << 3) | (k & 7);
        cw1b[dst] = to_b16(conv_w1[i]);
        return;
    }
    i -= 262144;
    if (i < 262144){
        int o = (i >> 8) & 255, k = i & 255;
        int dst = (i & ~65535) | ((k >> 3) << 11) | (o << 3) | (k & 7);
        cw2b[dst] = to_b16(conv_w2[i]);
        return;
    }
    i -= 262144;
    if (i < 65536){
        int o = i >> 8, k2 = i & 255;
        float v = (o < 128) ? mu_w[o*256 + k2] : lv_w[(o-128)*256 + k2];
        mvwpk[i] = pack_hl(v);
        if (i < 256) mvb[i] = (i < 128) ? mu_b[i] : lv_b[i-128];
        return;
    }
    i -= 65536;
    if (i < 131072){
        int flow = i >> 15;
        int o  = (i >> 7) & 255;
        int kk = i & 127;
        float v = (kk <= (o % 127)) ? fw1[i] : 0.f;
        uint32_t h = bf16_rne_bits(v);
        int kc = kk >> 5, lq = (kk >> 3) & 3, e = kk & 7;
        size_t dst = (size_t)flow*65536 + (size_t)kc*16384 + (size_t)(lq*256 + o)*8 + e;
        w1p[dst]        = (uint16_t)(h >> 16);
        w1p[dst + 8192] = (uint16_t)(bf16_rne_bits(v - __uint_as_float(h)) >> 16);
        return;
    }
    i -= 131072;
    if (i < 262144){
        int flow = i >> 16;
        int o  = (i >> 8) & 255;
        int hh = i & 255;
        float v = ((hh % 127) < (o & 127)) ? fw2[i] : 0.f;
        uint32_t h = bf16_rne_bits(v);
        int kc = hh >> 5, lq = (hh >> 3) & 3, e = hh & 7;
        size_t dst = (size_t)flow*131072 + (size_t)kc*16384 + (size_t)(lq*256 + o)*8 + e;
        w2p[dst]        = (uint16_t)(h >> 16);
        w2p[dst + 8192] = (uint16_t)(bf16_rne_bits(v - __uint_as_float(h)) >> 16);
        return;
    }
    i -= 262144;
    if (i < 32768){ dnw1b[i] = to_b16(dn_w1[i]); return; }
    i -= 32768;
    if (i < 393216){           // node-decoder W2: 1444 rows padded to 1536, packed
        int o = i >> 8, k = i & 255;
        float v = (o < MA*NNF_) ? dn_w2[(size_t)o*256 + k] : 0.f;
        size_t dst = (size_t)(o >> 8)*65536 + (size_t)(k >> 5)*8192
                   + (size_t)((k >> 3) & 3)*2048 + (size_t)(o & 255)*8 + (size_t)(k & 7);
        dnw2b[dst] = to_b16(v);
        return;
    }
    i -= 393216;
    if (i < 65536){ dew1b[i] = to_b16(de_w1[i]); return; }
    i -= 65536;
    if (i < 3014656){          // edge-decoder W2: symmetrized, 5776 rows padded to 5888, packed
        int o = i >> 9, k = i & 511;
        float v = 0.f;
        if (o < MA*MA*NEF_){
            int e = o & 3, cell = o >> 2;
            int ii = cell / MA, jj = cell - ii*MA;
            int ot = (jj*MA + ii)*4 + e;
            v = 0.5f*(de_w2[(size_t)o*512 + k] + de_w2[(size_t)ot*512 + k]);
            if (k == 0) deb2s[o] = 0.5f*(de_b2[o] + de_b2[ot]);
        }
        size_t dst = (size_t)(o >> 8)*131072 + (size_t)(k >> 5)*8192
                   + (size_t)((k >> 3) & 3)*2048 + (size_t)(o & 255)*8 + (size_t)(k & 7);
        dew2b[dst] = to_b16(v);
    }
}

// ---------------- fused conv v9: single W buffer, 48KB LDS, 3 blocks/CU ----------------
// R13 lesson: 48us was invariant across three SCHEDULES, all at 8 waves/CU.
// Unexplored axis = occupancy. Single 16KB W buffer (the dbuf bought nothing
// under __syncthreads drain) -> 48KB LDS -> 3 blocks/CU = 12 waves/CU
// (+50% TLP) and 768 blocks = exactly one generation (3 x 256, no tail).
// Cost: stage latency exposed per chunk (2 barriers/chunk) -- covered by
// the extra resident blocks.

__global__ __launch_bounds__(256) void k_conv2(
    const uint16_t* __restrict__ A,
    const uint16_t* __restrict__ W1p, const float* __restrict__ B1,
    const uint16_t* __restrict__ W2p, const float* __restrict__ B2,
    uint16_t* __restrict__ C)
{
    extern __shared__ __align__(16) char smem[];   // [0,32K) A/h1/out, [32K,48K) W
    const int tid  = threadIdx.x;
    const int wave = tid >> 6;
    const int lane = tid & 63;
    const int l15  = lane & 15;
    const int lq   = lane >> 4;
    const int l7   = lane & 7;
    const int row0 = blockIdx.x * 64;
    char* wb = smem + 32768;

    #define STAGE_W(Wp, kc)                                                  \
        { _Pragma("unroll")                                                  \
          for (int it=0; it<4; ++it){                                        \
            int s = it*256 + tid;                                            \
            __builtin_amdgcn_global_load_lds(                                \
                (const __attribute__((address_space(1))) uint32_t*)          \
                    ((const char*)(Wp) + (size_t)(kc)*16384 + (size_t)s*16), \
                (__attribute__((address_space(3))) uint32_t*)(wb + s*16),    \
                16, 0, 0);                                                   \
          } }

    #pragma unroll
    for (int it = 0; it < 8; ++it) {
        int s  = it*256 + tid;
        int m  = s >> 5;
        int gl = (s & 31) ^ (m & 7);
        const char* gp = (const char*)A + ((size_t)(row0+m)*HIDDEN)*2 + gl*16;
        __builtin_amdgcn_global_load_lds(
            (const __attribute__((address_space(1))) uint32_t*)gp,
            (__attribute__((address_space(3))) uint32_t*)(smem + (size_t)s*16),
            16, 0, 0);
    }
    STAGE_W(W1p, 0);
    __syncthreads();          // A + W1c0 ready

    f32x4 acc[4][4];
    #pragma unroll
    for (int mt=0;mt<4;mt++)
        #pragma unroll
        for (int nt=0;nt<4;nt++) acc[mt][nt] = (f32x4)(0.f);

    #pragma unroll
    for (int kc = 0; kc < 8; ++kc){
        bf16x8 bw[4];
        #pragma unroll
        for (int nt=0;nt<4;nt++)
            bw[nt] = *(const bf16x8*)(wb + (size_t)((lq*256 + wave*64 + nt*16 + l15)) * 16);
        #pragma unroll
        for (int mt=0;mt<4;mt++){
            const int mb = (mt*16 + l15) << 5;
            int g = kc*4 + lq;
            bf16x8 a = *(const bf16x8*)(smem + (size_t)(mb + (g ^ l7))*16);
            #pragma unroll
            for (int nt=0;nt<4;nt++)
                acc[mt][nt] = MFMA16(a, bw[nt], acc[mt][nt], 0, 0, 0);
        }
        __syncthreads();      // all reads of wb done
        if (kc < 7){ STAGE_W(W1p, kc+1); } else { STAGE_W(W2p, 0); }
        __syncthreads();      // staged chunk ready
    }

    // epilogue1 -> h1 into A region
    uint16_t* h1 = (uint16_t*)smem;
    #pragma unroll
    for (int mt=0;mt<4;mt++){
        #pragma unroll
        for (int nt=0;nt<4;nt++){
            int col = wave*64 + nt*16 + l15;
            float bb = B1[col];
            #pragma unroll
            for (int reg=0;reg<4;reg++){
                int r = mt*16 + lq*4 + reg;
                float v = fmaxf(acc[mt][nt][reg] + bb, 0.f);
                h1[(r*32 + ((col>>3) ^ (r&7)))*8 + (col&7)] = to_b16(v);
            }
        }
    }
    __syncthreads();          // h1 visible (W2c0 already resident)

    #pragma unroll
    for (int mt=0;mt<4;mt++)
        #pragma unroll
        for (int nt=0;nt<4;nt++) acc[mt][nt] = (f32x4)(0.f);

    #pragma unroll
    for (int kc = 0; kc < 8; ++kc){
        bf16x8 bw[4];
        #pragma unroll
        for (int nt=0;nt<4;nt++)
            bw[nt] = *(const bf16x8*)(wb + (size_t)((lq*256 + wave*64 + nt*16 + l15)) * 16);
        #pragma unroll
        for (int mt=0;mt<4;mt++){
            int m = mt*16 + l15;
            bf16x8 a = *(const bf16x8*)(h1 + (size_t)(m*32 + ((kc*4 + lq) ^ (m & 7)))*8);
            #pragma unroll
            for (int nt=0;nt<4;nt++)
                acc[mt][nt] = MFMA16(a, bw[nt], acc[mt][nt], 0, 0, 0);
        }
        __syncthreads();
        if (kc < 7){
            STAGE_W(W2p, kc+1);
            __syncthreads();
        }
    }

    uint16_t* rs = (uint16_t*)smem;
    #pragma unroll
    for (int mt=0;mt<4;mt++){
        #pragma unroll
        for (int nt=0;nt<4;nt++){
            int col = wave*64 + nt*16 + l15;
            float bb = B2[col];
            #pragma unroll
            for (int reg=0;reg<4;reg++){
                int r = mt*16 + lq*4 + reg;
                float v = fmaxf(acc[mt][nt][reg] + bb, 0.f);
                rs[(r*32 + ((col>>3) ^ (r&7)))*8 + (col&7)] = to_b16(v);
            }
        }
    }
    BARRIER();

    #pragma unroll
    for (int it = 0; it < 8; ++it){
        int s   = it*256 + tid;
        int row = s >> 5;
        int gc  = s & 31;
        uint4 d = *(const uint4*)(smem + (size_t)(row*32 + (gc ^ (row & 7)))*16);
        *(uint4*)(C + (size_t)(row0+row)*HIDDEN + gc*8) = d;
    }
    #undef STAGE_W
}

// ---------------- MFMA GEMM (mu/lv + decoders) ----------------

template<int SPLIT, int OUTM, int PACKED = 0>
__global__ __launch_bounds__(256) void mfma_gemm(
    const void* __restrict__ Ap, const void* __restrict__ Wp,
    const float* __restrict__ bias, void* __restrict__ Cp,
    int M, int N, int K, int relu)
{
    extern __shared__ __align__(16) char smem[];
    const int tid  = threadIdx.x;
    const int wave = tid >> 6;
    const int lane = tid & 63;
    const int l15  = lane & 15;
    const int lq   = lane >> 4;
    const int l7   = lane & 7;
    const int row0 = blockIdx.y * 64;
    const int n0   = blockIdx.x * 256;
    const int ELB  = SPLIT ? 4 : 2;
    const int KC   = (K < 256) ? K : 256;
    const int GR   = (KC * ELB) >> 4;
    const int rsh  = (GR == 64) ? 6 : ((GR == 32) ? 5 : 4);

    f32x4 acc[4][4];
    #pragma unroll
    for (int mt=0;mt<4;mt++)
        #pragma unroll
        for (int nt=0;nt<4;nt++) acc[mt][nt] = (f32x4)(0.f);

    const char* Ab = (const char*)Ap;
    const char* Wb = (const char*)Wp;
    const char* Wsl = Wb + (size_t)blockIdx.x * (size_t)K * 512;
    char* wbp0 = smem + 32768;
    char* wbp1 = smem + 32768 + 16384;
    int pb = 0;
    const int NCH = K >> 5;

    #define STAGE_PK(ch, wb)                                                 \
        { _Pragma("unroll")                                                  \
          for (int it=0; it<4; ++it){                                        \
            int s = it*256 + tid;                                            \
            __builtin_amdgcn_global_load_lds(                                \
                (const __attribute__((address_space(1))) uint32_t*)          \
                    (Wsl + (size_t)(ch)*16384 + (size_t)s*16),               \
                (__attribute__((address_space(3))) uint32_t*)((wb) + s*16),  \
                16, 0, 0);                                                   \
          } }

    for (int kbase = 0; kbase < K; kbase += KC) {
        const int rounds = GR >> 2;
        for (int it = 0; it < rounds; ++it) {
            int sbase = it*256 + wave*64;
            int s  = sbase + lane;
            int m  = s >> rsh;
            int gl = (s & (GR-1)) ^ (m & 7);
            const char* gp = Ab + ((size_t)(row0+m)*K + kbase)*ELB + gl*16;
            __builtin_amdgcn_global_load_lds(
                (const __attribute__((address_space(1))) uint32_t*)gp,
                (__attribute__((address_space(3))) uint32_t*)(smem + sbase*16),
                16, 0, 0);
        }
        if (PACKED && kbase == 0) STAGE_PK(0, wbp0);
        if (!PACKED) __syncthreads();

        for (int kc = 0; kc < (KC >> 5); ++kc) {
            bf16x8 bhi[4], blo[4];
            if (PACKED){
                int gch = (kbase >> 5) + kc;
                char* rdb = pb ? wbp1 : wbp0;
                if (gch + 1 < NCH){ char* stb = pb ? wbp0 : wbp1; STAGE_PK(gch+1, stb); WAITV4(); }
                else { WAITV0(); }
                SBAR();
                #pragma unroll
                for (int nt=0;nt<4;nt++)
                    bhi[nt] = *(const bf16x8*)(rdb + (size_t)(lq*256 + wave*64 + nt*16 + l15)*16);
            } else {
                #pragma unroll
                for (int nt=0;nt<4;nt++){
                    int n = n0 + wave*64 + nt*16 + l15;
                    if (n >= N) n = N-1;
                    if (SPLIT){
                        const uint4* wp4 = (const uint4*)(Wb + ((size_t)n*K + kbase + kc*32 + lq*8)*4);
                        uint4 xx = wp4[0], yy = wp4[1];
                        unpack_frag(xx, yy, bhi[nt], blo[nt]);
                    } else {
                        bhi[nt] = *(const bf16x8*)(Wb + ((size_t)n*K + kbase + kc*32 + lq*8)*2);
                    }
                }
            }
            #pragma unroll
            for (int mt=0;mt<4;mt++){
                const int mb = (mt*16 + l15) << rsh;
                if (SPLIT){
                    int g0 = kc*8 + lq*2;
                    uint4 xx = *(const uint4*)(smem + (size_t)(mb + ((g0  ) ^ l7))*16);
                    uint4 yy = *(const uint4*)(smem + (size_t)(mb + ((g0+1) ^ l7))*16);
                    bf16x8 ahi, alo;
                    unpack_frag(xx, yy, ahi, alo);
                    #pragma unroll
                    for (int nt=0;nt<4;nt++){
                        acc[mt][nt] = MFMA16(ahi, bhi[nt], acc[mt][nt], 0, 0, 0);
                        acc[mt][nt] = MFMA16(ahi, blo[nt], acc[mt][nt], 0, 0, 0);
                        acc[mt][nt] = MFMA16(alo, bhi[nt], acc[mt][nt], 0, 0, 0);
                    }
                } else {
                    int g = kc*4 + lq;
                    bf16x8 a = *(const bf16x8*)(smem + (size_t)(mb + (g ^ l7))*16);
                    #pragma unroll
                    for (int nt=0;nt<4;nt++){
                        acc[mt][nt] = MFMA16(a, bhi[nt], acc[mt][nt], 0, 0, 0);
                    }
                }
            }
            if (PACKED){ SBAR(); pb ^= 1; }
        }
        if (!PACKED) __syncthreads(); else SBAR();
    }

    const int ES = (OUTM == 1) ? 2 : 4;
    char* rs = smem + wave*(64*64*ES);
    const int colbase = n0 + wave*64;
    #pragma unroll
    for (int mt=0;mt<4;mt++){
        #pragma unroll
        for (int nt=0;nt<4;nt++){
            int cl = nt*16 + l15;
            int col = colbase + cl;
            float bb = bias[col < N ? col : N-1];
            #pragma unroll
            for (int reg=0;reg<4;reg++){
                int r = mt*16 + lq*4 + reg;
                float v = acc[mt][nt][reg] + bb;
                if (relu) v = fmaxf(v, 0.f);
                if (OUTM == 1) ((uint16_t*)rs)[r*64 + cl] = to_b16(v);
                else           ((float*)rs)[r*64 + cl] = v;
            }
        }
    }
    __syncthreads();
    for (int it = 0; it < 32; ++it) {
        int r   = it*2 + (lane>>5);
        int clp = lane & 31;
        int col = colbase + clp*2;
        if (col < N){
            if (OUTM == 1){
                uint32_t d = *(const uint32_t*)((const uint16_t*)rs + r*64 + clp*2);
                *(uint32_t*)((char*)Cp + ((size_t)(row0+r)*N + col)*2) = d;
            } else {
                float2 d = *(const float2*)((const float*)rs + r*64 + clp*2);
                *(float2*)((float*)Cp + (size_t)(row0+r)*N + col) = d;
            }
        }
    }
    #undef STAGE_PK
}

// ---------------- pooling + z0 elementwise ----------------

__global__ void k_pool(const uint16_t* __restrict__ h, const int* __restrict__ gstart,
                       const int* __restrict__ gcnt, uint32_t* __restrict__ hg){
    int b = blockIdx.x; int c = threadIdx.x;
    int s0 = gstart[b]; int n = gcnt[b];
    float s = 0.f;
    for (int j=0;j<n;j++) s += from_b16(h[(size_t)(s0+j)*HIDDEN + c]);
    hg[(size_t)b*HIDDEN + c] = pack_hl(s);
}

__global__ void k_z0(const float* __restrict__ mv, const float* __restrict__ eps,
                     float* __restrict__ mu_o, float* __restrict__ lv_o, float* __restrict__ z0_o){
    int i = blockIdx.x*256 + threadIdx.x;
    if (i >= NB*LAT) return;
    int b = i >> 7, l = i & 127;
    float m = mv[(size_t)b*256 + l];
    float v = mv[(size_t)b*256 + l + 128];
    mu_o[i] = m;
    lv_o[i] = v;
    z0_o[i] = m + eps[i]*expf(0.5f*v);
}

// ---------------- fused MFMA flows v8: LDS-streamed weights + counted vmcnt ----------------

__global__ __launch_bounds__(1024) void k_flows_mfma8(
    const float* __restrict__ z0,
    const uint16_t* __restrict__ w1p, const float* __restrict__ fb1,
    const uint16_t* __restrict__ w2p, const float* __restrict__ fb2,
    float* __restrict__ zK, uint16_t* __restrict__ zkb, float* __restrict__ sld)
{
    __shared__ __align__(16) uint16_t zhi[16][136];
    __shared__ __align__(16) uint16_t zlo[16][136];
    __shared__ __align__(16) uint16_t h1hi[16][280];
    __shared__ __align__(16) uint16_t h1lo[16][280];
    __shared__ __align__(16) float    oS[16][268];
    __shared__ __align__(16) uint16_t wbuf[2][16384];
    const int tid  = threadIdx.x;
    const int wave = tid >> 6;
    const int lane = tid & 63;
    const int l15  = lane & 15;
    const int lq   = lane >> 4;
    const int g0   = blockIdx.x * 16;
    const int col  = wave*16 + l15;
    const int fo   = (lq*256 + col)*8;

    #define STAGE_C(srcp, buf)                                               \
        { _Pragma("unroll")                                                  \
          for (int it=0; it<2; ++it){                                        \
            int s = it*1024 + tid;                                           \
            __builtin_amdgcn_global_load_lds(                                \
                (const __attribute__((address_space(1))) uint32_t*)          \
                    ((const char*)(srcp) + (size_t)s*16),                    \
                (__attribute__((address_space(3))) uint32_t*)                \
                    ((char*)&wbuf[buf][0] + (size_t)s*16),                   \
                16, 0, 0);                                                   \
          } }

    int pb = 0;
    STAGE_C(w1p, 0);

    float b1r[4], b2r[4];
    #pragma unroll
    for (int kf=0;kf<4;kf++){
        b1r[kf] = fb1[kf*FHID + col];
        b2r[kf] = fb2[kf*2*LAT + col];
    }
    asm volatile("" : "+v"(b1r[0]),"+v"(b1r[1]),"+v"(b1r[2]),"+v"(b1r[3]),
                      "+v"(b2r[0]),"+v"(b2r[1]),"+v"(b2r[2]),"+v"(b2r[3]));

    #pragma unroll
    for (int q=0;q<2;q++){
        int idx = q*1024 + tid;
        int r = idx >> 7, l = idx & 127;
        float v = z0[(size_t)(g0 + r)*LAT + l];
        uint32_t h = bf16_rne_bits(v);
        zhi[r][l] = (uint16_t)(h >> 16);
        zlo[r][l] = (uint16_t)(bf16_rne_bits(v - __uint_as_float(h)) >> 16);
    }
    float ldacc = 0.f;
    asm volatile("s_waitcnt vmcnt(0) lgkmcnt(0)" ::: "memory");
    __builtin_amdgcn_sched_barrier(0);
    SBAR();

    for (int kf=0; kf<NFLOWS; kf++){
        const uint16_t* W1f = w1p + (size_t)kf*65536;
        const uint16_t* W2f = w2p + (size_t)kf*131072;

        // ---- GEMM1: 4 chunks ----
        f32x4 acc = (f32x4)(0.f);
        #pragma unroll
        for (int kc=0;kc<4;kc++){
            const uint16_t* nxt = (kc < 3) ? (W1f + (size_t)(kc+1)*16384) : W2f;
            STAGE_C(nxt, pb^1);
            WAITV2();
            SBAR();
            bf16x8 wh = *(const bf16x8*)&wbuf[pb][fo];
            bf16x8 wl = *(const bf16x8*)&wbuf[pb][fo + 8192];
            bf16x8 ah = *(const bf16x8*)&zhi[l15][kc*32 + lq*8];
            bf16x8 al = *(const bf16x8*)&zlo[l15][kc*32 + lq*8];
            acc = MFMA16(ah, wh, acc, 0, 0, 0);
            acc = MFMA16(ah, wl, acc, 0, 0, 0);
            acc = MFMA16(al, wh, acc, 0, 0, 0);
            SBAR();
            pb ^= 1;
        }
        {
            #pragma unroll
            for (int reg=0;reg<4;reg++){
                int r = lq*4 + reg;
                float v = fmaxf(acc[reg] + b1r[kf], 0.f);
                uint32_t h = bf16_rne_bits(v);
                h1hi[r][col] = (uint16_t)(h >> 16);
                h1lo[r][col] = (uint16_t)(bf16_rne_bits(v - __uint_as_float(h)) >> 16);
            }
        }
        BARRIER();   // lgkm only: h1 visible; W2 chunk0 still streaming

        // ---- GEMM2: 8 chunks ----
        f32x4 a2 = (f32x4)(0.f);
        #pragma unroll
        for (int kc=0;kc<8;kc++){
            if (kc < 7){
                STAGE_C(W2f + (size_t)(kc+1)*16384, pb^1);
                WAITV2();
            } else if (kf < NFLOWS-1){
                STAGE_C(w1p + (size_t)(kf+1)*65536, pb^1);
                WAITV2();
            } else {
                WAITV0();
            }
            SBAR();
            bf16x8 wh = *(const bf16x8*)&wbuf[pb][fo];
            bf16x8 wl = *(const bf16x8*)&wbuf[pb][fo + 8192];
            bf16x8 ah = *(const bf16x8*)&h1hi[l15][kc*32 + lq*8];
            bf16x8 al = *(const bf16x8*)&h1lo[l15][kc*32 + lq*8];
            a2 = MFMA16(ah, wh, a2, 0, 0, 0);
            a2 = MFMA16(ah, wl, a2, 0, 0, 0);
            a2 = MFMA16(al, wh, a2, 0, 0, 0);
            SBAR();
            pb ^= 1;
        }
        {
            #pragma unroll
            for (int reg=0;reg<4;reg++)
                oS[lq*4 + reg][col] = a2[reg] + b2r[kf];
        }
        BARRIER();

        // ---- z update + log-det ----
        {
            const int r = wave;
            float ldp = 0.f;
            #pragma unroll
            for (int j=0;j<2;j++){
                int l = lane + j*64;
                float m = oS[r][l];
                float s = oS[r][l + 128];
                float g = 1.f/(1.f + expf(-s));
                float zv = __uint_as_float((uint32_t)zhi[r][l] << 16)
                         + __uint_as_float((uint32_t)zlo[r][l] << 16);
                float zn = g*zv + (1.f - g)*m;
                uint32_t h = bf16_rne_bits(zn);
                zhi[r][l] = (uint16_t)(h >> 16);
                zlo[r][l] = (uint16_t)(bf16_rne_bits(zn - __uint_as_float(h)) >> 16);
                ldp += logf(g + 1e-8f);
            }
            #pragma unroll
            for (int off=1; off<64; off<<=1) ldp += __shfl_xor(ldp, off);
            ldacc += ldp;
        }
        BARRIER();
    }

    #pragma unroll
    for (int q=0;q<2;q++){
        int idx = q*1024 + tid;
        int r = idx >> 7, l = idx & 127;
        uint32_t h = (uint32_t)zhi[r][l] << 16;
        float zv = __uint_as_float(h) + __uint_as_float((uint32_t)zlo[r][l] << 16);
        zK[(size_t)(g0+r)*LAT + l] = zv;
        zkb[(size_t)(g0+r)*LAT + l] = (uint16_t)(h >> 16);
    }
    if (lane == 0) sld[g0 + wave] = ldacc;
    #undef STAGE_C
}

// ---------------- launch ----------------

extern "C" void kernel_launch(void* const* d_in, const int* in_sizes, int n_in,
                              void* d_out, int out_size, void* d_ws, size_t ws_size,
                              hipStream_t stream){
    (void)in_sizes; (void)n_in; (void)out_size; (void)ws_size;
    const int*   x        = (const int*)d_in[0];
    const int*   eidx     = (const int*)d_in[1];
    const int*   eattr    = (const int*)d_in[2];
    const int*   batch    = (const int*)d_in[3];
    const float* eps      = (const float*)d_in[4];
    const float* node_emb = (const float*)d_in[5];
    const float* edge_emb = (const float*)d_in[6];
    const float* conv_w1  = (const float*)d_in[7];
    const float* conv_b1  = (const float*)d_in[8];
    const float* conv_w2  = (const float*)d_in[9];
    const float* conv_b2  = (const float*)d_in[10];
    const float* mu_w     = (const float*)d_in[11];
    const float* mu_b     = (const float*)d_in[12];
    const float* lv_w     = (const float*)d_in[13];
    const float* lv_b     = (const float*)d_in[14];
    const float* fw1      = (const float*)d_in[15];
    const float* fb1      = (const float*)d_in[16];
    const float* fw2      = (const float*)d_in[17];
    const float* fb2      = (const float*)d_in[18];
    const float* dn_w1    = (const float*)d_in[19];
    const float* dn_b1    = (const float*)d_in[20];
    const float* dn_w2    = (const float*)d_in[21];
    const float* dn_b2    = (const float*)d_in[22];
    const float* de_w1    = (const float*)d_in[23];
    const float* de_b1    = (const float*)d_in[24];
    const float* de_w2    = (const float*)d_in[25];
    const float* de_b2    = (const float*)d_in[26];

    float* out = (float*)d_out;
    const size_t off_node = 0;
    const size_t off_edge = (size_t)NB*MA*NNF_;
    const size_t off_mu   = off_edge + (size_t)NB*MA*MA*NEF_;
    const size_t off_lv   = off_mu + (size_t)NB*LAT;
    const size_t off_z0   = off_lv + (size_t)NB*LAT;
    const size_t off_zk   = off_z0 + (size_t)NB*LAT;
    const size_t off_sld  = off_zk + (size_t)NB*LAT;
    (void)off_node;

    char* p = (char*)d_ws;
    auto alloc = [&](size_t bytes)->char*{ char* r = p; p += (bytes + 255) & ~(size_t)255; return r; };
    uint16_t* h_b   = (uint16_t*)alloc((size_t)N_NODES*HIDDEN*2);
    uint16_t* t_b   = (uint16_t*)alloc((size_t)N_NODES*HIDDEN*2);
    int*   offs   = (int*)  alloc((size_t)(N_NODES+1)*4);
    int*   cursor = (int*)  alloc((size_t)N_NODES*4);
    int*   epack  = (int*)  alloc((size_t)N_EDGES*4);
    int*   gstart = (int*)  alloc((size_t)NB*4);
    int*   gcnt   = (int*)  alloc((size_t)NB*4);
    uint32_t* hg_pk = (uint32_t*)alloc((size_t)NB*HIDDEN*4);
    float* mv       = (float*)alloc((size_t)NB*256*4);
    uint16_t* cw1b  = (uint16_t*)alloc((size_t)4*HIDDEN*HIDDEN*2);
    uint16_t* cw2b  = (uint16_t*)alloc((size_t)4*HIDDEN*HIDDEN*2);
    uint32_t* mvwpk = (uint32_t*)alloc((size_t)256*256*4);
    float*    mvb   = (float*)  alloc((size_t)256*4);
    uint16_t* w1p   = (uint16_t*)alloc((size_t)NFLOWS*65536*2);
    uint16_t* w2p   = (uint16_t*)alloc((size_t)NFLOWS*131072*2);
    uint16_t* dnw1b = (uint16_t*)alloc((size_t)256*LAT*2);
    uint16_t* dnw2b = (uint16_t*)alloc((size_t)1536*256*2);
    uint16_t* dew1b = (uint16_t*)alloc((size_t)512*LAT*2);
    uint16_t* dew2b = (uint16_t*)alloc((size_t)5888*512*2);
    float*    deb2s = (float*)  alloc((size_t)MA*MA*NEF_*4);
    uint16_t* zkb   = (uint16_t*)alloc((size_t)NB*LAT*2);
    uint16_t* hnb   = (uint16_t*)alloc((size_t)NB*256*2);
    uint16_t* heb   = (uint16_t*)alloc((size_t)NB*512*2);

    const int* esrc = eidx;
    const int* edst = eidx + N_EDGES;

    k_cvt_all<<<(CVT_TOTAL+255)/256, 256, 0, stream>>>(
        conv_w1, conv_w2, mu_w, mu_b, lv_w, lv_b, fw1, fw2,
        dn_w1, dn_w2, de_w1, de_w2, de_b2,
        cw1b, cw2b, mvwpk, mvb, w1p, w2p,
        dnw1b, dnw2b, dew1b, dew2b, deb2s);

    k_init   <<<(N_NODES+255)/256, 256, 0, stream>>>(cursor, gstart, gcnt);
    k_embed  <<<N_NODES, HIDDEN, 0, stream>>>(x, node_emb, h_b);
    k_deg    <<<(N_EDGES+255)/256, 256, 0, stream>>>(edst, cursor);
    k_meta   <<<(N_NODES+255)/256, 256, 0, stream>>>(batch, gstart, gcnt);
    k_scan   <<<1, 1024, 0, stream>>>(cursor, offs);
    k_scatter<<<(N_EDGES+255)/256, 256, 0, stream>>>(esrc, edst, eattr, offs, cursor, epack);

    const size_t SM32 = 32768, SM48 = 49152, SM64 = 65536;
    for (int k=0;k<4;k++){
        k_aggr<<<N_NODES/4, 256, 0, stream>>>(h_b, edge_emb, offs, epack, t_b);
        k_conv2<<<N_NODES/64, 256, SM48, stream>>>(
            t_b,
            cw1b + (size_t)k*HIDDEN*HIDDEN, conv_b1 + (size_t)k*HIDDEN,
            cw2b + (size_t)k*HIDDEN*HIDDEN, conv_b2 + (size_t)k*HIDDEN,
            h_b);
    }

    k_pool<<<NB, HIDDEN, 0, stream>>>(h_b, gstart, gcnt, hg_pk);
    mfma_gemm<1,2><<<dim3(1, NB/64), 256, SM64, stream>>>(hg_pk, mvwpk, mvb, mv, NB, 256, HIDDEN, 0);
    k_z0<<<(NB*LAT+255)/256, 256, 0, stream>>>(mv, eps, out+off_mu, out+off_lv, out+off_z0);

    k_flows_mfma8<<<NB/16, 1024, 0, stream>>>(out+off_z0, w1p, fb1, w2p, fb2,
                                              out+off_zk, zkb, out+off_sld);

    mfma_gemm<0,1><<<dim3(1, NB/64), 256, SM32, stream>>>(zkb, dnw1b, dn_b1, hnb, NB, 256, LAT, 1);
    mfma_gemm<0,2,1><<<dim3(6, NB/64), 256, SM64, stream>>>(hnb, dnw2b, dn_b2, out+off_node, NB, MA*NNF_, 256, 0);
    mfma_gemm<0,1><<<dim3(2, NB/64), 256, SM32, stream>>>(zkb, dew1b, de_b1, heb, NB, 512, LAT, 1);
    mfma_gemm<0,2,1><<<dim3(23, NB/64), 256, SM64, stream>>>(heb, dew2b, deb2s, out+off_edge, NB, MA*MA*NEF_, 512, 0);
}

// Round 15
// 528.590 us; speedup vs baseline: 1.0477x; 1.0477x over previous
//
#include <hip/hip_runtime.h>
#include <hip/hip_bf16.h>
#include <math.h>
#include <stdint.h>

#define N_NODES 49152
#define N_EDGES 196608
#define NB      2048
#define HIDDEN  256
#define LAT     128
#define FHID    256
#define NFLOWS  4
#define MA      38
#define NNF_    38
#define NEF_    4

typedef __attribute__((ext_vector_type(8))) short bf16x8;
typedef __attribute__((ext_vector_type(4))) float f32x4;

#define MEMPIN() asm volatile("" ::: "memory")
#define BARRIER() asm volatile("s_waitcnt lgkmcnt(0)\n\ts_barrier" ::: "memory")
#define SBAR() __builtin_amdgcn_s_barrier()
#define WAITV0() { asm volatile("s_waitcnt vmcnt(0)" ::: "memory"); __builtin_amdgcn_sched_barrier(0); }
#define WAITV2() { asm volatile("s_waitcnt vmcnt(2)" ::: "memory"); __builtin_amdgcn_sched_barrier(0); }
#define WAITV4() { asm volatile("s_waitcnt vmcnt(4)" ::: "memory"); __builtin_amdgcn_sched_barrier(0); }
#define MFMA16 __builtin_amdgcn_mfma_f32_16x16x32_bf16

// ---------- bf16 helpers ----------
__device__ inline uint32_t bf16_rne_bits(float v){
    uint32_t u = __float_as_uint(v);
    u += 0x7fffu + ((u >> 16) & 1u);
    return u & 0xffff0000u;
}
__device__ inline uint16_t to_b16(float v){ return (uint16_t)(bf16_rne_bits(v) >> 16); }
__device__ inline float from_b16(uint16_t u){ return __uint_as_float((uint32_t)u << 16); }
__device__ inline uint32_t pack_hl(float v){
    uint32_t hu = bf16_rne_bits(v);
    float r = v - __uint_as_float(hu);
    uint32_t lu = bf16_rne_bits(r);
    return hu | (lu >> 16);
}

__device__ inline void unpack_frag(const uint4& x, const uint4& y, bf16x8& hi, bf16x8& lo){
    union { bf16x8 v; uint32_t u[4]; } H, L;
    H.u[0] = __builtin_amdgcn_perm(x.y, x.x, 0x07060302u);
    H.u[1] = __builtin_amdgcn_perm(x.w, x.z, 0x07060302u);
    H.u[2] = __builtin_amdgcn_perm(y.y, y.x, 0x07060302u);
    H.u[3] = __builtin_amdgcn_perm(y.w, y.z, 0x07060302u);
    L.u[0] = __builtin_amdgcn_perm(x.y, x.x, 0x05040100u);
    L.u[1] = __builtin_amdgcn_perm(x.w, x.z, 0x05040100u);
    L.u[2] = __builtin_amdgcn_perm(y.y, y.x, 0x05040100u);
    L.u[3] = __builtin_amdgcn_perm(y.w, y.z, 0x05040100u);
    hi = H.v; lo = L.v;
}

// ---------------- init / CSR build ----------------

__global__ void k_init(int* __restrict__ cursor, int* __restrict__ gstart, int* __restrict__ gcnt){
    int i = blockIdx.x*256 + threadIdx.x;
    if (i < N_NODES) cursor[i] = 0;
    if (i < NB){ gstart[i] = 0x7fffffff; gcnt[i] = 0; }
}

__global__ void k_embed(const int* __restrict__ x, const float* __restrict__ emb, uint16_t* __restrict__ h){
    int i = blockIdx.x; int c = threadIdx.x;
    h[(size_t)i*HIDDEN + c] = to_b16(emb[x[i]*HIDDEN + c]);
}

__global__ void k_deg(const int* __restrict__ dst, int* __restrict__ cursor){
    int e = blockIdx.x*256 + threadIdx.x;
    if (e < N_EDGES) atomicAdd(&cursor[dst[e]], 1);
}

__global__ void k_meta(const int* __restrict__ batch, int* __restrict__ gstart, int* __restrict__ gcnt){
    int i = blockIdx.x*256 + threadIdx.x;
    if (i < N_NODES){ int b = batch[i]; atomicMin(&gstart[b], i); atomicAdd(&gcnt[b], 1); }
}

__global__ __launch_bounds__(1024) void k_scan(int* __restrict__ cursor, int* __restrict__ offs){
    __shared__ int part[1024];
    const int tid = threadIdx.x;
    const int CH = N_NODES/1024; // 48
    int local[48];
    int s = 0;
    int base = tid*CH;
    for (int j=0;j<CH;j++){ local[j] = cursor[base+j]; s += local[j]; }
    part[tid] = s;
    __syncthreads();
    for (int off=1; off<1024; off<<=1){
        int v = (tid>=off) ? part[tid-off] : 0;
        __syncthreads();
        part[tid] += v;
        __syncthreads();
    }
    int excl = (tid==0) ? 0 : part[tid-1];
    for (int j=0;j<CH;j++){ offs[base+j] = excl; excl += local[j]; cursor[base+j] = 0; }
    if (tid == 1023) offs[N_NODES] = excl;
}

__global__ void k_scatter(const int* __restrict__ src, const int* __restrict__ dst, const int* __restrict__ attr,
                          const int* __restrict__ offs, int* __restrict__ cursor, int* __restrict__ epack){
    int e = blockIdx.x*256 + threadIdx.x;
    if (e < N_EDGES){
        int d = dst[e];
        int pos = atomicAdd(&cursor[d], 1);
        epack[offs[d] + pos] = (src[e] & 0xffff) | (attr[e] << 16);
    }
}

// ---------------- message aggregation: wave-per-node, 4-edge MLP chunks ----------------

__global__ __launch_bounds__(256) void k_aggr(const uint16_t* __restrict__ h, const float* __restrict__ eemb,
                                              const int* __restrict__ offs, const int* __restrict__ epack,
                                              uint16_t* __restrict__ t){
    __shared__ float sE[NEF_*HIDDEN];
    const int tid  = threadIdx.x;
    #pragma unroll
    for (int q=0;q<NEF_;q++) sE[q*256 + tid] = eemb[q*256 + tid];
    __syncthreads();

    const int wave = tid >> 6;
    const int lane = tid & 63;
    const int node = blockIdx.x*4 + wave;
    const int c4   = lane*4;

    uint2 hu = *(const uint2*)(h + (size_t)node*HIDDEN + c4);
    float4 acc;
    acc.x = __uint_as_float(hu.x << 16);
    acc.y = __uint_as_float(hu.x & 0xffff0000u);
    acc.z = __uint_as_float(hu.y << 16);
    acc.w = __uint_as_float(hu.y & 0xffff0000u);

    const int e0 = offs[node], e1 = offs[node+1];
    for (int j = e0; j < e1; j += 4){
        int p0 = epack[j];
        int p1 = (j+1 < e1) ? epack[j+1] : p0;
        int p2 = (j+2 < e1) ? epack[j+2] : p0;
        int p3 = (j+3 < e1) ? epack[j+3] : p0;
        uint2 g0 = *(const uint2*)(h + (size_t)(p0 & 0xffff)*HIDDEN + c4);
        uint2 g1 = *(const uint2*)(h + (size_t)(p1 & 0xffff)*HIDDEN + c4);
        uint2 g2 = *(const uint2*)(h + (size_t)(p2 & 0xffff)*HIDDEN + c4);
        uint2 g3 = *(const uint2*)(h + (size_t)(p3 & 0xffff)*HIDDEN + c4);
        {
            const float4 ev = *(const float4*)&sE[(p0 >> 16)*HIDDEN + c4];
            acc.x += fmaxf(__uint_as_float(g0.x << 16)        + ev.x, 0.f);
            acc.y += fmaxf(__uint_as_float(g0.x & 0xffff0000u) + ev.y, 0.f);
            acc.z += fmaxf(__uint_as_float(g0.y << 16)        + ev.z, 0.f);
            acc.w += fmaxf(__uint_as_float(g0.y & 0xffff0000u) + ev.w, 0.f);
        }
        if (j+1 < e1){
            const float4 ev = *(const float4*)&sE[(p1 >> 16)*HIDDEN + c4];
            acc.x += fmaxf(__uint_as_float(g1.x << 16)        + ev.x, 0.f);
            acc.y += fmaxf(__uint_as_float(g1.x & 0xffff0000u) + ev.y, 0.f);
            acc.z += fmaxf(__uint_as_float(g1.y << 16)        + ev.z, 0.f);
            acc.w += fmaxf(__uint_as_float(g1.y & 0xffff0000u) + ev.w, 0.f);
        }
        if (j+2 < e1){
            const float4 ev = *(const float4*)&sE[(p2 >> 16)*HIDDEN + c4];
            acc.x += fmaxf(__uint_as_float(g2.x << 16)        + ev.x, 0.f);
            acc.y += fmaxf(__uint_as_float(g2.x & 0xffff0000u) + ev.y, 0.f);
            acc.z += fmaxf(__uint_as_float(g2.y << 16)        + ev.z, 0.f);
            acc.w += fmaxf(__uint_as_float(g2.y & 0xffff0000u) + ev.w, 0.f);
        }
        if (j+3 < e1){
            const float4 ev = *(const float4*)&sE[(p3 >> 16)*HIDDEN + c4];
            acc.x += fmaxf(__uint_as_float(g3.x << 16)        + ev.x, 0.f);
            acc.y += fmaxf(__uint_as_float(g3.x & 0xffff0000u) + ev.y, 0.f);
            acc.z += fmaxf(__uint_as_float(g3.y << 16)        + ev.z, 0.f);
            acc.w += fmaxf(__uint_as_float(g3.y & 0xffff0000u) + ev.w, 0.f);
        }
    }

    uint2 o;
    o.x = (uint32_t)to_b16(acc.x) | ((uint32_t)to_b16(acc.y) << 16);
    o.y = (uint32_t)to_b16(acc.z) | ((uint32_t)to_b16(acc.w) << 16);
    *(uint2*)(t + (size_t)node*HIDDEN + c4) = o;
}

// ---------------- fused weight / activation converter (single launch) ----------------

#define CVT_TOTAL 4489216

__global__ void k_cvt_all(
    const float* __restrict__ conv_w1, const float* __restrict__ conv_w2,
    const float* __restrict__ mu_w, const float* __restrict__ mu_b,
    const float* __restrict__ lv_w, const float* __restrict__ lv_b,
    const float* __restrict__ fw1, const float* __restrict__ fw2,
    const float* __restrict__ dn_w1, const float* __restrict__ dn_w2,
    const float* __restrict__ de_w1, const float* __restrict__ de_w2,
    const float* __restrict__ de_b2,
    uint16_t* __restrict__ cw1b, uint16_t* __restrict__ cw2b,
    uint32_t* __restrict__ mvwpk, float* __restrict__ mvb,
    uint16_t* __restrict__ w1p, uint16_t* __restrict__ w2p,
    uint16_t* __restrict__ dnw1b, uint16_t* __restrict__ dnw2b,
    uint16_t* __restrict__ dew1b, uint16_t* __restrict__ dew2b,
    float* __restrict__ deb2s)
{
    int i = blockIdx.x*256 + threadIdx.x;
    if (i < 262144){
        int o = (i >> 8) & 255, k = i & 255;
        int dst = (i & ~65535) | ((k >> 3) << 11) | (o << 3) | (k & 7);
        cw1b[dst] = to_b16(conv_w1[i]);
        return;
    }
    i -= 262144;
    if (i < 262144){
        int o = (i >> 8) & 255, k = i & 255;
        int dst = (i & ~65535) | ((k >> 3) << 11) | (o << 3) | (k & 7);
        cw2b[dst] = to_b16(conv_w2[i]);
        return;
    }
    i -= 262144;
    if (i < 65536){
        int o = i >> 8, k2 = i & 255;
        float v = (o < 128) ? mu_w[o*256 + k2] : lv_w[(o-128)*256 + k2];
        mvwpk[i] = pack_hl(v);
        if (i < 256) mvb[i] = (i < 128) ? mu_b[i] : lv_b[i-128];
        return;
    }
    i -= 65536;
    if (i < 131072){
        int flow = i >> 15;
        int o  = (i >> 7) & 255;
        int kk = i & 127;
        float v = (kk <= (o % 127)) ? fw1[i] : 0.f;
        uint32_t h = bf16_rne_bits(v);
        int kc = kk >> 5, lq = (kk >> 3) & 3, e = kk & 7;
        size_t dst = (size_t)flow*65536 + (size_t)kc*16384 + (size_t)(lq*256 + o)*8 + e;
        w1p[dst]        = (uint16_t)(h >> 16);
        w1p[dst + 8192] = (uint16_t)(bf16_rne_bits(v - __uint_as_float(h)) >> 16);
        return;
    }
    i -= 131072;
    if (i < 262144){
        int flow = i >> 16;
        int o  = (i >> 8) & 255;
        int hh = i & 255;
        float v = ((hh % 127) < (o & 127)) ? fw2[i] : 0.f;
        uint32_t h = bf16_rne_bits(v);
        int kc = hh >> 5, lq = (hh >> 3) & 3, e = hh & 7;
        size_t dst = (size_t)flow*131072 + (size_t)kc*16384 + (size_t)(lq*256 + o)*8 + e;
        w2p[dst]        = (uint16_t)(h >> 16);
        w2p[dst + 8192] = (uint16_t)(bf16_rne_bits(v - __uint_as_float(h)) >> 16);
        return;
    }
    i -= 262144;
    if (i < 32768){ dnw1b[i] = to_b16(dn_w1[i]); return; }
    i -= 32768;
    if (i < 393216){           // node-decoder W2: 1444 rows padded to 1536, packed
        int o = i >> 8, k = i & 255;
        float v = (o < MA*NNF_) ? dn_w2[(size_t)o*256 + k] : 0.f;
        size_t dst = (size_t)(o >> 8)*65536 + (size_t)(k >> 5)*8192
                   + (size_t)((k >> 3) & 3)*2048 + (size_t)(o & 255)*8 + (size_t)(k & 7);
        dnw2b[dst] = to_b16(v);
        return;
    }
    i -= 393216;
    if (i < 65536){ dew1b[i] = to_b16(de_w1[i]); return; }
    i -= 65536;
    if (i < 3014656){          // edge-decoder W2: symmetrized, 5776 rows padded to 5888, packed
        int o = i >> 9, k = i & 511;
        float v = 0.f;
        if (o < MA*MA*NEF_){
            int e = o & 3, cell = o >> 2;
            int ii = cell / MA, jj = cell - ii*MA;
            int ot = (jj*MA + ii)*4 + e;
            v = 0.5f*(de_w2[(size_t)o*512 + k] + de_w2[(size_t)ot*512 + k]);
            if (k == 0) deb2s[o] = 0.5f*(de_b2[o] + de_b2[ot]);
        }
        size_t dst = (size_t)(o >> 8)*131072 + (size_t)(k >> 5)*8192
                   + (size_t)((k >> 3) & 3)*2048 + (size_t)(o & 255)*8 + (size_t)(k & 7);
        dew2b[dst] = to_b16(v);
    }
}

// ---------------- fused conv v10: WAVE-PRIVATE W staging, zero K-loop barriers ----------------
// 15-round record: conv2 ~48us under 4 variants that all share cross-wave
// barriers coupling the W stream (every wave stalls at every chunk). v10
// removes the coupling: each wave stages ONLY its own 4KB of W strips
// (4 x 1KB at lq*4096 + wave*1024 within the packed 16KB chunk) into a
// wave-private 2x4KB dbuf, ordered by per-wave vmcnt(4). Barriers: 4 total
// (post-initial-stage drain; lgkm-only pair around the h1 epilogue; one
// before copy-out). Waves free-run -> stage latency overlaps MFMA across
// drifted waves. Loop-body VMEM = exactly the 4 stage loads (biases
// preloaded+pinned), so counted waits are exact. LDS 64KB -> 2 blocks/CU.

__global__ __launch_bounds__(256) void k_conv2(
    const uint16_t* __restrict__ A,
    const uint16_t* __restrict__ W1p, const float* __restrict__ B1,
    const uint16_t* __restrict__ W2p, const float* __restrict__ B2,
    uint16_t* __restrict__ C)
{
    __shared__ __align__(16) char sA[32768];
    __shared__ __align__(16) char sWv[4][2][4096];   // [wave][buf][strips]
    const int tid  = threadIdx.x;
    const int wave = tid >> 6;
    const int lane = tid & 63;
    const int l15  = lane & 15;
    const int lq   = lane >> 4;
    const int l7   = lane & 7;
    const int row0 = blockIdx.x * 64;

    // stage the wave's 4 strips (1KB each) of global chunk g into buf g&1
    #define STAGE_WV(g)                                                      \
        { const uint16_t* Wsrc_ = ((g) < 8) ? W1p : W2p;                     \
          const int cc_ = ((g) < 8) ? (g) : ((g) - 8);                       \
          char* dst_ = sWv[wave][(g) & 1];                                   \
          _Pragma("unroll")                                                  \
          for (int i_=0; i_<4; ++i_){                                        \
            __builtin_amdgcn_global_load_lds(                                \
                (const __attribute__((address_space(1))) uint32_t*)          \
                    ((const char*)Wsrc_ + (size_t)cc_*16384 + (size_t)i_*4096 \
                     + (size_t)wave*1024 + (size_t)lane*16),                 \
                (__attribute__((address_space(3))) uint32_t*)(dst_ + i_*1024), \
                16, 0, 0);                                                   \
          } }

    // stage A: 64 rows x 512B = 32KB, granule-swizzled (block-wide)
    #pragma unroll
    for (int it = 0; it < 8; ++it) {
        int s  = it*256 + tid;
        int m  = s >> 5;
        int gl = (s & 31) ^ (m & 7);
        const char* gp = (const char*)A + ((size_t)(row0+m)*HIDDEN)*2 + gl*16;
        __builtin_amdgcn_global_load_lds(
            (const __attribute__((address_space(1))) uint32_t*)gp,
            (__attribute__((address_space(3))) uint32_t*)(sA + (size_t)s*16),
            16, 0, 0);
    }
    // bias preload + pin (keeps the K loops free of compiler VMEM loads)
    float b1r[4], b2r[4];
    #pragma unroll
    for (int nt=0;nt<4;nt++){
        b1r[nt] = B1[wave*64 + nt*16 + l15];
        b2r[nt] = B2[wave*64 + nt*16 + l15];
    }
    asm volatile("" : "+v"(b1r[0]),"+v"(b1r[1]),"+v"(b1r[2]),"+v"(b1r[3]),
                      "+v"(b2r[0]),"+v"(b2r[1]),"+v"(b2r[2]),"+v"(b2r[3]));
    STAGE_WV(0);
    __syncthreads();          // full drain: A + biases + W chunk0 ready

    f32x4 acc[4][4];
    #pragma unroll
    for (int mt=0;mt<4;mt++)
        #pragma unroll
        for (int nt=0;nt<4;nt++) acc[mt][nt] = (f32x4)(0.f);

    // ---- GEMM1: chunks g = 0..7, NO barriers (wave-private stream) ----
    #pragma unroll
    for (int kc = 0; kc < 8; ++kc){
        STAGE_WV(kc+1);       // next chunk (kc=7 stages W2 chunk0)
        WAITV4();             // chunk kc's 4 strips landed; next stays in flight
        const char* wb = sWv[wave][kc & 1];
        bf16x8 bw[4];
        #pragma unroll
        for (int nt=0;nt<4;nt++)
            bw[nt] = *(const bf16x8*)(wb + (size_t)(lq*1024 + (nt*16 + l15)*16));
        #pragma unroll
        for (int mt=0;mt<4;mt++){
            const int mb = (mt*16 + l15) << 5;
            int g = kc*4 + lq;
            bf16x8 a = *(const bf16x8*)(sA + (size_t)(mb + (g ^ l7))*16);
            #pragma unroll
            for (int nt=0;nt<4;nt++)
                acc[mt][nt] = MFMA16(a, bw[nt], acc[mt][nt], 0, 0, 0);
        }
    }

    BARRIER();                // lgkm-only: all waves' A reads done; W stream in flight

    // epilogue1 -> h1 into the A region (disjoint per-wave column bands)
    uint16_t* h1 = (uint16_t*)sA;
    #pragma unroll
    for (int mt=0;mt<4;mt++){
        #pragma unroll
        for (int nt=0;nt<4;nt++){
            int col = wave*64 + nt*16 + l15;
            #pragma unroll
            for (int reg=0;reg<4;reg++){
                int r = mt*16 + lq*4 + reg;
                float v = fmaxf(acc[mt][nt][reg] + b1r[nt], 0.f);
                h1[(r*32 + ((col>>3) ^ (r&7)))*8 + (col&7)] = to_b16(v);
            }
            acc[mt][nt] = (f32x4)(0.f);
        }
    }
    BARRIER();                // lgkm-only: h1 visible; W2 chunk0 still in flight

    // ---- GEMM2: chunks g = 8..15, NO barriers ----
    #pragma unroll
    for (int kc = 0; kc < 8; ++kc){
        const int g = 8 + kc;
        if (g < 15){ STAGE_WV(g+1); WAITV4(); } else { WAITV0(); }
        const char* wb = sWv[wave][g & 1];
        bf16x8 bw[4];
        #pragma unroll
        for (int nt=0;nt<4;nt++)
            bw[nt] = *(const bf16x8*)(wb + (size_t)(lq*1024 + (nt*16 + l15)*16));
        #pragma unroll
        for (int mt=0;mt<4;mt++){
            int m = mt*16 + l15;
            bf16x8 a = *(const bf16x8*)(h1 + (size_t)(m*32 + ((kc*4 + lq) ^ (m & 7)))*8);
            #pragma unroll
            for (int nt=0;nt<4;nt++)
                acc[mt][nt] = MFMA16(a, bw[nt], acc[mt][nt], 0, 0, 0);
        }
    }
    BARRIER();                // all waves' h1 reads done -> region reusable

    // epilogue2 -> A region, stage-style swizzle for coalesced copy-out
    uint16_t* rs = (uint16_t*)sA;
    #pragma unroll
    for (int mt=0;mt<4;mt++){
        #pragma unroll
        for (int nt=0;nt<4;nt++){
            int col = wave*64 + nt*16 + l15;
            #pragma unroll
            for (int reg=0;reg<4;reg++){
                int r = mt*16 + lq*4 + reg;
                float v = fmaxf(acc[mt][nt][reg] + b2r[nt], 0.f);
                rs[(r*32 + ((col>>3) ^ (r&7)))*8 + (col&7)] = to_b16(v);
            }
        }
    }
    BARRIER();

    #pragma unroll
    for (int it = 0; it < 8; ++it){
        int s   = it*256 + tid;
        int row = s >> 5;
        int gc  = s & 31;
        uint4 d = *(const uint4*)(sA + (size_t)(row*32 + (gc ^ (row & 7)))*16);
        *(uint4*)(C + (size_t)(row0+row)*HIDDEN + gc*8) = d;
    }
    #undef STAGE_WV
}

// ---------------- MFMA GEMM (mu/lv + decoders) ----------------

template<int SPLIT, int OUTM, int PACKED = 0>
__global__ __launch_bounds__(256) void mfma_gemm(
    const void* __restrict__ Ap, const void* __restrict__ Wp,
    const float* __restrict__ bias, void* __restrict__ Cp,
    int M, int N, int K, int relu)
{
    extern __shared__ __align__(16) char smem[];
    const int tid  = threadIdx.x;
    const int wave = tid >> 6;
    const int lane = tid & 63;
    const int l15  = lane & 15;
    const int lq   = lane >> 4;
    const int l7   = lane & 7;
    const int row0 = blockIdx.y * 64;
    const int n0   = blockIdx.x * 256;
    const int ELB  = SPLIT ? 4 : 2;
    const int KC   = (K < 256) ? K : 256;
    const int GR   = (KC * ELB) >> 4;
    const int rsh  = (GR == 64) ? 6 : ((GR == 32) ? 5 : 4);

    f32x4 acc[4][4];
    #pragma unroll
    for (int mt=0;mt<4;mt++)
        #pragma unroll
        for (int nt=0;nt<4;nt++) acc[mt][nt] = (f32x4)(0.f);

    const char* Ab = (const char*)Ap;
    const char* Wb = (const char*)Wp;
    const char* Wsl = Wb + (size_t)blockIdx.x * (size_t)K * 512;
    char* wbp0 = smem + 32768;
    char* wbp1 = smem + 32768 + 16384;
    int pb = 0;
    const int NCH = K >> 5;

    #define STAGE_PK(ch, wb)                                                 \
        { _Pragma("unroll")                                                  \
          for (int it=0; it<4; ++it){                                        \
            int s = it*256 + tid;                                            \
            __builtin_amdgcn_global_load_lds(                                \
                (const __attribute__((address_space(1))) uint32_t*)          \
                    (Wsl + (size_t)(ch)*16384 + (size_t)s*16),               \
                (__attribute__((address_space(3))) uint32_t*)((wb) + s*16),  \
                16, 0, 0);                                                   \
          } }

    for (int kbase = 0; kbase < K; kbase += KC) {
        const int rounds = GR >> 2;
        for (int it = 0; it < rounds; ++it) {
            int sbase = it*256 + wave*64;
            int s  = sbase + lane;
            int m  = s >> rsh;
            int gl = (s & (GR-1)) ^ (m & 7);
            const char* gp = Ab + ((size_t)(row0+m)*K + kbase)*ELB + gl*16;
            __builtin_amdgcn_global_load_lds(
                (const __attribute__((address_space(1))) uint32_t*)gp,
                (__attribute__((address_space(3))) uint32_t*)(smem + sbase*16),
                16, 0, 0);
        }
        if (PACKED && kbase == 0) STAGE_PK(0, wbp0);
        if (!PACKED) __syncthreads();

        for (int kc = 0; kc < (KC >> 5); ++kc) {
            bf16x8 bhi[4], blo[4];
            if (PACKED){
                int gch = (kbase >> 5) + kc;
                char* rdb = pb ? wbp1 : wbp0;
                if (gch + 1 < NCH){ char* stb = pb ? wbp0 : wbp1; STAGE_PK(gch+1, stb); WAITV4(); }
                else { WAITV0(); }
                SBAR();
                #pragma unroll
                for (int nt=0;nt<4;nt++)
                    bhi[nt] = *(const bf16x8*)(rdb + (size_t)(lq*256 + wave*64 + nt*16 + l15)*16);
            } else {
                #pragma unroll
                for (int nt=0;nt<4;nt++){
                    int n = n0 + wave*64 + nt*16 + l15;
                    if (n >= N) n = N-1;
                    if (SPLIT){
                        const uint4* wp4 = (const uint4*)(Wb + ((size_t)n*K + kbase + kc*32 + lq*8)*4);
                        uint4 xx = wp4[0], yy = wp4[1];
                        unpack_frag(xx, yy, bhi[nt], blo[nt]);
                    } else {
                        bhi[nt] = *(const bf16x8*)(Wb + ((size_t)n*K + kbase + kc*32 + lq*8)*2);
                    }
                }
            }
            #pragma unroll
            for (int mt=0;mt<4;mt++){
                const int mb = (mt*16 + l15) << rsh;
                if (SPLIT){
                    int g0 = kc*8 + lq*2;
                    uint4 xx = *(const uint4*)(smem + (size_t)(mb + ((g0  ) ^ l7))*16);
                    uint4 yy = *(const uint4*)(smem + (size_t)(mb + ((g0+1) ^ l7))*16);
                    bf16x8 ahi, alo;
                    unpack_frag(xx, yy, ahi, alo);
                    #pragma unroll
                    for (int nt=0;nt<4;nt++){
                        acc[mt][nt] = MFMA16(ahi, bhi[nt], acc[mt][nt], 0, 0, 0);
                        acc[mt][nt] = MFMA16(ahi, blo[nt], acc[mt][nt], 0, 0, 0);
                        acc[mt][nt] = MFMA16(alo, bhi[nt], acc[mt][nt], 0, 0, 0);
                    }
                } else {
                    int g = kc*4 + lq;
                    bf16x8 a = *(const bf16x8*)(smem + (size_t)(mb + (g ^ l7))*16);
                    #pragma unroll
                    for (int nt=0;nt<4;nt++){
                        acc[mt][nt] = MFMA16(a, bhi[nt], acc[mt][nt], 0, 0, 0);
                    }
                }
            }
            if (PACKED){ SBAR(); pb ^= 1; }
        }
        if (!PACKED) __syncthreads(); else SBAR();
    }

    const int ES = (OUTM == 1) ? 2 : 4;
    char* rs = smem + wave*(64*64*ES);
    const int colbase = n0 + wave*64;
    #pragma unroll
    for (int mt=0;mt<4;mt++){
        #pragma unroll
        for (int nt=0;nt<4;nt++){
            int cl = nt*16 + l15;
            int col = colbase + cl;
            float bb = bias[col < N ? col : N-1];
            #pragma unroll
            for (int reg=0;reg<4;reg++){
                int r = mt*16 + lq*4 + reg;
                float v = acc[mt][nt][reg] + bb;
                if (relu) v = fmaxf(v, 0.f);
                if (OUTM == 1) ((uint16_t*)rs)[r*64 + cl] = to_b16(v);
                else           ((float*)rs)[r*64 + cl] = v;
            }
        }
    }
    __syncthreads();
    for (int it = 0; it < 32; ++it) {
        int r   = it*2 + (lane>>5);
        int clp = lane & 31;
        int col = colbase + clp*2;
        if (col < N){
            if (OUTM == 1){
                uint32_t d = *(const uint32_t*)((const uint16_t*)rs + r*64 + clp*2);
                *(uint32_t*)((char*)Cp + ((size_t)(row0+r)*N + col)*2) = d;
            } else {
                float2 d = *(const float2*)((const float*)rs + r*64 + clp*2);
                *(float2*)((float*)Cp + (size_t)(row0+r)*N + col) = d;
            }
        }
    }
    #undef STAGE_PK
}

// ---------------- pooling + z0 elementwise ----------------

__global__ void k_pool(const uint16_t* __restrict__ h, const int* __restrict__ gstart,
                       const int* __restrict__ gcnt, uint32_t* __restrict__ hg){
    int b = blockIdx.x; int c = threadIdx.x;
    int s0 = gstart[b]; int n = gcnt[b];
    float s = 0.f;
    for (int j=0;j<n;j++) s += from_b16(h[(size_t)(s0+j)*HIDDEN + c]);
    hg[(size_t)b*HIDDEN + c] = pack_hl(s);
}

__global__ void k_z0(const float* __restrict__ mv, const float* __restrict__ eps,
                     float* __restrict__ mu_o, float* __restrict__ lv_o, float* __restrict__ z0_o){
    int i = blockIdx.x*256 + threadIdx.x;
    if (i >= NB*LAT) return;
    int b = i >> 7, l = i & 127;
    float m = mv[(size_t)b*256 + l];
    float v = mv[(size_t)b*256 + l + 128];
    mu_o[i] = m;
    lv_o[i] = v;
    z0_o[i] = m + eps[i]*expf(0.5f*v);
}

// ---------------- fused MFMA flows v8: LDS-streamed weights + counted vmcnt ----------------

__global__ __launch_bounds__(1024) void k_flows_mfma8(
    const float* __restrict__ z0,
    const uint16_t* __restrict__ w1p, const float* __restrict__ fb1,
    const uint16_t* __restrict__ w2p, const float* __restrict__ fb2,
    float* __restrict__ zK, uint16_t* __restrict__ zkb, float* __restrict__ sld)
{
    __shared__ __align__(16) uint16_t zhi[16][136];
    __shared__ __align__(16) uint16_t zlo[16][136];
    __shared__ __align__(16) uint16_t h1hi[16][280];
    __shared__ __align__(16) uint16_t h1lo[16][280];
    __shared__ __align__(16) float    oS[16][268];
    __shared__ __align__(16) uint16_t wbuf[2][16384];
    const int tid  = threadIdx.x;
    const int wave = tid >> 6;
    const int lane = tid & 63;
    const int l15  = lane & 15;
    const int lq   = lane >> 4;
    const int g0   = blockIdx.x * 16;
    const int col  = wave*16 + l15;
    const int fo   = (lq*256 + col)*8;

    #define STAGE_C(srcp, buf)                                               \
        { _Pragma("unroll")                                                  \
          for (int it=0; it<2; ++it){                                        \
            int s = it*1024 + tid;                                           \
            __builtin_amdgcn_global_load_lds(                                \
                (const __attribute__((address_space(1))) uint32_t*)          \
                    ((const char*)(srcp) + (size_t)s*16),                    \
                (__attribute__((address_space(3))) uint32_t*)                \
                    ((char*)&wbuf[buf][0] + (size_t)s*16),                   \
                16, 0, 0);                                                   \
          } }

    int pb = 0;
    STAGE_C(w1p, 0);

    float b1r[4], b2r[4];
    #pragma unroll
    for (int kf=0;kf<4;kf++){
        b1r[kf] = fb1[kf*FHID + col];
        b2r[kf] = fb2[kf*2*LAT + col];
    }
    asm volatile("" : "+v"(b1r[0]),"+v"(b1r[1]),"+v"(b1r[2]),"+v"(b1r[3]),
                      "+v"(b2r[0]),"+v"(b2r[1]),"+v"(b2r[2]),"+v"(b2r[3]));

    #pragma unroll
    for (int q=0;q<2;q++){
        int idx = q*1024 + tid;
        int r = idx >> 7, l = idx & 127;
        float v = z0[(size_t)(g0 + r)*LAT + l];
        uint32_t h = bf16_rne_bits(v);
        zhi[r][l] = (uint16_t)(h >> 16);
        zlo[r][l] = (uint16_t)(bf16_rne_bits(v - __uint_as_float(h)) >> 16);
    }
    float ldacc = 0.f;
    asm volatile("s_waitcnt vmcnt(0) lgkmcnt(0)" ::: "memory");
    __builtin_amdgcn_sched_barrier(0);
    SBAR();

    for (int kf=0; kf<NFLOWS; kf++){
        const uint16_t* W1f = w1p + (size_t)kf*65536;
        const uint16_t* W2f = w2p + (size_t)kf*131072;

        // ---- GEMM1: 4 chunks ----
        f32x4 acc = (f32x4)(0.f);
        #pragma unroll
        for (int kc=0;kc<4;kc++){
            const uint16_t* nxt = (kc < 3) ? (W1f + (size_t)(kc+1)*16384) : W2f;
            STAGE_C(nxt, pb^1);
            WAITV2();
            SBAR();
            bf16x8 wh = *(const bf16x8*)&wbuf[pb][fo];
            bf16x8 wl = *(const bf16x8*)&wbuf[pb][fo + 8192];
            bf16x8 ah = *(const bf16x8*)&zhi[l15][kc*32 + lq*8];
            bf16x8 al = *(const bf16x8*)&zlo[l15][kc*32 + lq*8];
            acc = MFMA16(ah, wh, acc, 0, 0, 0);
            acc = MFMA16(ah, wl, acc, 0, 0, 0);
            acc = MFMA16(al, wh, acc, 0, 0, 0);
            SBAR();
            pb ^= 1;
        }
        {
            #pragma unroll
            for (int reg=0;reg<4;reg++){
                int r = lq*4 + reg;
                float v = fmaxf(acc[reg] + b1r[kf], 0.f);
                uint32_t h = bf16_rne_bits(v);
                h1hi[r][col] = (uint16_t)(h >> 16);
                h1lo[r][col] = (uint16_t)(bf16_rne_bits(v - __uint_as_float(h)) >> 16);
            }
        }
        BARRIER();   // lgkm only: h1 visible; W2 chunk0 still streaming

        // ---- GEMM2: 8 chunks ----
        f32x4 a2 = (f32x4)(0.f);
        #pragma unroll
        for (int kc=0;kc<8;kc++){
            if (kc < 7){
                STAGE_C(W2f + (size_t)(kc+1)*16384, pb^1);
                WAITV2();
            } else if (kf < NFLOWS-1){
                STAGE_C(w1p + (size_t)(kf+1)*65536, pb^1);
                WAITV2();
            } else {
                WAITV0();
            }
            SBAR();
            bf16x8 wh = *(const bf16x8*)&wbuf[pb][fo];
            bf16x8 wl = *(const bf16x8*)&wbuf[pb][fo + 8192];
            bf16x8 ah = *(const bf16x8*)&h1hi[l15][kc*32 + lq*8];
            bf16x8 al = *(const bf16x8*)&h1lo[l15][kc*32 + lq*8];
            a2 = MFMA16(ah, wh, a2, 0, 0, 0);
            a2 = MFMA16(ah, wl, a2, 0, 0, 0);
            a2 = MFMA16(al, wh, a2, 0, 0, 0);
            SBAR();
            pb ^= 1;
        }
        {
            #pragma unroll
            for (int reg=0;reg<4;reg++)
                oS[lq*4 + reg][col] = a2[reg] + b2r[kf];
        }
        BARRIER();

        // ---- z update + log-det ----
        {
            const int r = wave;
            float ldp = 0.f;
            #pragma unroll
            for (int j=0;j<2;j++){
                int l = lane + j*64;
                float m = oS[r][l];
                float s = oS[r][l + 128];
                float g = 1.f/(1.f + expf(-s));
                float zv = __uint_as_float((uint32_t)zhi[r][l] << 16)
                         + __uint_as_float((uint32_t)zlo[r][l] << 16);
                float zn = g*zv + (1.f - g)*m;
                uint32_t h = bf16_rne_bits(zn);
                zhi[r][l] = (uint16_t)(h >> 16);
                zlo[r][l] = (uint16_t)(bf16_rne_bits(zn - __uint_as_float(h)) >> 16);
                ldp += logf(g + 1e-8f);
            }
            #pragma unroll
            for (int off=1; off<64; off<<=1) ldp += __shfl_xor(ldp, off);
            ldacc += ldp;
        }
        BARRIER();
    }

    #pragma unroll
    for (int q=0;q<2;q++){
        int idx = q*1024 + tid;
        int r = idx >> 7, l = idx & 127;
        uint32_t h = (uint32_t)zhi[r][l] << 16;
        float zv = __uint_as_float(h) + __uint_as_float((uint32_t)zlo[r][l] << 16);
        zK[(size_t)(g0+r)*LAT + l] = zv;
        zkb[(size_t)(g0+r)*LAT + l] = (uint16_t)(h >> 16);
    }
    if (lane == 0) sld[g0 + wave] = ldacc;
    #undef STAGE_C
}

// ---------------- launch ----------------

extern "C" void kernel_launch(void* const* d_in, const int* in_sizes, int n_in,
                              void* d_out, int out_size, void* d_ws, size_t ws_size,
                              hipStream_t stream){
    (void)in_sizes; (void)n_in; (void)out_size; (void)ws_size;
    const int*   x        = (const int*)d_in[0];
    const int*   eidx     = (const int*)d_in[1];
    const int*   eattr    = (const int*)d_in[2];
    const int*   batch    = (const int*)d_in[3];
    const float* eps      = (const float*)d_in[4];
    const float* node_emb = (const float*)d_in[5];
    const float* edge_emb = (const float*)d_in[6];
    const float* conv_w1  = (const float*)d_in[7];
    const float* conv_b1  = (const float*)d_in[8];
    const float* conv_w2  = (const float*)d_in[9];
    const float* conv_b2  = (const float*)d_in[10];
    const float* mu_w     = (const float*)d_in[11];
    const float* mu_b     = (const float*)d_in[12];
    const float* lv_w     = (const float*)d_in[13];
    const float* lv_b     = (const float*)d_in[14];
    const float* fw1      = (const float*)d_in[15];
    const float* fb1      = (const float*)d_in[16];
    const float* fw2      = (const float*)d_in[17];
    const float* fb2      = (const float*)d_in[18];
    const float* dn_w1    = (const float*)d_in[19];
    const float* dn_b1    = (const float*)d_in[20];
    const float* dn_w2    = (const float*)d_in[21];
    const float* dn_b2    = (const float*)d_in[22];
    const float* de_w1    = (const float*)d_in[23];
    const float* de_b1    = (const float*)d_in[24];
    const float* de_w2    = (const float*)d_in[25];
    const float* de_b2    = (const float*)d_in[26];

    float* out = (float*)d_out;
    const size_t off_node = 0;
    const size_t off_edge = (size_t)NB*MA*NNF_;
    const size_t off_mu   = off_edge + (size_t)NB*MA*MA*NEF_;
    const size_t off_lv   = off_mu + (size_t)NB*LAT;
    const size_t off_z0   = off_lv + (size_t)NB*LAT;
    const size_t off_zk   = off_z0 + (size_t)NB*LAT;
    const size_t off_sld  = off_zk + (size_t)NB*LAT;
    (void)off_node;

    char* p = (char*)d_ws;
    auto alloc = [&](size_t bytes)->char*{ char* r = p; p += (bytes + 255) & ~(size_t)255; return r; };
    uint16_t* h_b   = (uint16_t*)alloc((size_t)N_NODES*HIDDEN*2);
    uint16_t* t_b   = (uint16_t*)alloc((size_t)N_NODES*HIDDEN*2);
    int*   offs   = (int*)  alloc((size_t)(N_NODES+1)*4);
    int*   cursor = (int*)  alloc((size_t)N_NODES*4);
    int*   epack  = (int*)  alloc((size_t)N_EDGES*4);
    int*   gstart = (int*)  alloc((size_t)NB*4);
    int*   gcnt   = (int*)  alloc((size_t)NB*4);
    uint32_t* hg_pk = (uint32_t*)alloc((size_t)NB*HIDDEN*4);
    float* mv       = (float*)alloc((size_t)NB*256*4);
    uint16_t* cw1b  = (uint16_t*)alloc((size_t)4*HIDDEN*HIDDEN*2);
    uint16_t* cw2b  = (uint16_t*)alloc((size_t)4*HIDDEN*HIDDEN*2);
    uint32_t* mvwpk = (uint32_t*)alloc((size_t)256*256*4);
    float*    mvb   = (float*)  alloc((size_t)256*4);
    uint16_t* w1p   = (uint16_t*)alloc((size_t)NFLOWS*65536*2);
    uint16_t* w2p   = (uint16_t*)alloc((size_t)NFLOWS*131072*2);
    uint16_t* dnw1b = (uint16_t*)alloc((size_t)256*LAT*2);
    uint16_t* dnw2b = (uint16_t*)alloc((size_t)1536*256*2);
    uint16_t* dew1b = (uint16_t*)alloc((size_t)512*LAT*2);
    uint16_t* dew2b = (uint16_t*)alloc((size_t)5888*512*2);
    float*    deb2s = (float*)  alloc((size_t)MA*MA*NEF_*4);
    uint16_t* zkb   = (uint16_t*)alloc((size_t)NB*LAT*2);
    uint16_t* hnb   = (uint16_t*)alloc((size_t)NB*256*2);
    uint16_t* heb   = (uint16_t*)alloc((size_t)NB*512*2);

    const int* esrc = eidx;
    const int* edst = eidx + N_EDGES;

    k_cvt_all<<<(CVT_TOTAL+255)/256, 256, 0, stream>>>(
        conv_w1, conv_w2, mu_w, mu_b, lv_w, lv_b, fw1, fw2,
        dn_w1, dn_w2, de_w1, de_w2, de_b2,
        cw1b, cw2b, mvwpk, mvb, w1p, w2p,
        dnw1b, dnw2b, dew1b, dew2b, deb2s);

    k_init   <<<(N_NODES+255)/256, 256, 0, stream>>>(cursor, gstart, gcnt);
    k_embed  <<<N_NODES, HIDDEN, 0, stream>>>(x, node_emb, h_b);
    k_deg    <<<(N_EDGES+255)/256, 256, 0, stream>>>(edst, cursor);
    k_meta   <<<(N_NODES+255)/256, 256, 0, stream>>>(batch, gstart, gcnt);
    k_scan   <<<1, 1024, 0, stream>>>(cursor, offs);
    k_scatter<<<(N_EDGES+255)/256, 256, 0, stream>>>(esrc, edst, eattr, offs, cursor, epack);

    const size_t SM32 = 32768, SM64 = 65536;
    for (int k=0;k<4;k++){
        k_aggr<<<N_NODES/4, 256, 0, stream>>>(h_b, edge_emb, offs, epack, t_b);
        k_conv2<<<N_NODES/64, 256, 0, stream>>>(
            t_b,
            cw1b + (size_t)k*HIDDEN*HIDDEN, conv_b1 + (size_t)k*HIDDEN,
            cw2b + (size_t)k*HIDDEN*HIDDEN, conv_b2 + (size_t)k*HIDDEN,
            h_b);
    }

    k_pool<<<NB, HIDDEN, 0, stream>>>(h_b, gstart, gcnt, hg_pk);
    mfma_gemm<1,2><<<dim3(1, NB/64), 256, SM64, stream>>>(hg_pk, mvwpk, mvb, mv, NB, 256, HIDDEN, 0);
    k_z0<<<(NB*LAT+255)/256, 256, 0, stream>>>(mv, eps, out+off_mu, out+off_lv, out+off_z0);

    k_flows_mfma8<<<NB/16, 1024, 0, stream>>>(out+off_z0, w1p, fb1, w2p, fb2,
                                              out+off_zk, zkb, out+off_sld);

    mfma_gemm<0,1><<<dim3(1, NB/64), 256, SM32, stream>>>(zkb, dnw1b, dn_b1, hnb, NB, 256, LAT, 1);
    mfma_gemm<0,2,1><<<dim3(6, NB/64), 256, SM64, stream>>>(hnb, dnw2b, dn_b2, out+off_node, NB, MA*NNF_, 256, 0);
    mfma_gemm<0,1><<<dim3(2, NB/64), 256, SM32, stream>>>(zkb, dew1b, de_b1, heb, NB, 512, LAT, 1);
    mfma_gemm<0,2,1><<<dim3(23, NB/64), 256, SM64, stream>>>(heb, dew2b, deb2s, out+off_edge, NB, MA*MA*NEF_, 512, 0);
}